// Round 3
// baseline (161.601 us; speedup 1.0000x reference)
//
#include <hip/hip_runtime.h>

// Upsample 2x (nearest) + horizontal 1x16 FIR (flattened 4x4 kernel), SAME pad.
// x: (32,512,512,1) fp32, kernel: 16 fp32, out: (32,1024,1024,1) fp32.
//
// Structure:
//  - conv is horizontal-only and upsampled rows 2g,2g+1 are identical
//    -> output rows 2g,2g+1 identical: compute once, store twice.
//  - up[p]=x[p>>1] collapses the 16-tap FIR to 9-tap (even cols) / 8-tap
//    (odd cols) polyphase filters on x; zero-padding x by 4 each side makes
//    the collapsed form exact at boundaries.
//  - R2/R3: 8 rows per block (2048 blocks) to amortize barrier/weight setup,
//    float4 staging loads, ds_read_b64 fragment reads, nontemporal stores
//    (via clang ext_vector_type — HIP float4 is rejected by the builtin).

#define W_IN   512
#define H_IN   512
#define NB     32
#define W_OUT  1024
#define TILE_R 8
#define ROWSTRIDE 520   // 512 data + 4 zero halo each side

typedef float vf4 __attribute__((ext_vector_type(4)));

__global__ __launch_bounds__(256) void upsample_blur_kernel(
    const float* __restrict__ x,
    const float* __restrict__ kern,
    float* __restrict__ out)
{
    __shared__ float smem[TILE_R * ROWSTRIDE];

    const int t  = threadIdx.x;                 // 0..255
    const int g0 = blockIdx.x * TILE_R;         // global input row base (n*512+r flattened)

    // zero halos: 8 rows x 8 floats = 64 lanes
    if (t < TILE_R * 8) {
        const int rr = t >> 3;
        const int p  = t & 7;
        smem[rr * ROWSTRIDE + ((p < 4) ? p : 512 + p)] = 0.0f;
    }

    // stage TILE_R rows (16 KB) via float4: 1024 float4 units, 4 per thread
    const vf4* __restrict__ src4 =
        reinterpret_cast<const vf4*>(x + (size_t)g0 * W_IN);
#pragma unroll
    for (int i = 0; i < 4; ++i) {
        const int idx = t + 256 * i;            // 0..1023
        const int rr  = idx >> 7;               // idx / 128
        const int c4  = idx & 127;
        const vf4 v = src4[idx];
        *reinterpret_cast<vf4*>(&smem[rr * ROWSTRIDE + 4 + c4 * 4]) = v;
    }

    // collapsed polyphase weights (uniform; scalar-cached loads)
    float kf[16];
#pragma unroll
    for (int i = 0; i < 16; ++i) kf[i] = kern[i];
    float we[9], wo[8];
    we[0] = kf[0];
#pragma unroll
    for (int i = 0; i < 7; ++i) we[i + 1] = kf[2 * i + 1] + kf[2 * i + 2];
    we[8] = kf[15];
#pragma unroll
    for (int i = 0; i < 8; ++i) wo[i] = kf[2 * i] + kf[2 * i + 1];

    __syncthreads();

    // each thread: for each staged row, compute out cols 4t..4t+3 (u=2t,2t+1),
    // store identical float4 to output rows 2g and 2g+1.
#pragma unroll
    for (int rr = 0; rr < TILE_R; ++rr) {
        const float2* rowp =
            reinterpret_cast<const float2*>(&smem[rr * ROWSTRIDE]);
        // v[i] = row[2t + i], i=0..9  -> five ds_read_b64
        const float2 p0 = rowp[t];
        const float2 p1 = rowp[t + 1];
        const float2 p2 = rowp[t + 2];
        const float2 p3 = rowp[t + 3];
        const float2 p4 = rowp[t + 4];
        float v[10];
        v[0] = p0.x; v[1] = p0.y; v[2] = p1.x; v[3] = p1.y; v[4] = p2.x;
        v[5] = p2.y; v[6] = p3.x; v[7] = p3.y; v[8] = p4.x; v[9] = p4.y;

        float o0 = 0.f, o1 = 0.f, o2 = 0.f, o3 = 0.f;
#pragma unroll
        for (int j = 0; j < 9; ++j) o0 += we[j] * v[j];       // w=4t   (even)
#pragma unroll
        for (int j = 0; j < 8; ++j) o1 += wo[j] * v[j + 1];   // w=4t+1 (odd)
#pragma unroll
        for (int j = 0; j < 9; ++j) o2 += we[j] * v[j + 1];   // w=4t+2 (even)
#pragma unroll
        for (int j = 0; j < 8; ++j) o3 += wo[j] * v[j + 2];   // w=4t+3 (odd)

        vf4 o; o.x = o0; o.y = o1; o.z = o2; o.w = o3;
        const size_t g = (size_t)(g0 + rr);
        float* orow = out + 2 * g * (size_t)W_OUT;   // out row index = 2*g
        __builtin_nontemporal_store(o, reinterpret_cast<vf4*>(orow) + t);
        __builtin_nontemporal_store(o, reinterpret_cast<vf4*>(orow + W_OUT) + t);
    }
}

extern "C" void kernel_launch(void* const* d_in, const int* in_sizes, int n_in,
                              void* d_out, int out_size, void* d_ws, size_t ws_size,
                              hipStream_t stream) {
    const float* x    = (const float*)d_in[0];
    const float* kern = (const float*)d_in[1];
    float* out        = (float*)d_out;

    const int numBlocks = NB * H_IN / TILE_R;   // 2048 blocks, 8 rows each
    upsample_blur_kernel<<<numBlocks, 256, 0, stream>>>(x, kern, out);
}